// Round 1
// baseline (1644.961 us; speedup 1.0000x reference)
//
#include <hip/hip_runtime.h>

#define B_   32
#define CIN  128
#define HH   56
#define WW   56
#define COUT 256
#define QDIV 7.5f

// ---------- int8 dot4 helper ----------
__device__ __forceinline__ int dot4(int a, int b, int c) {
#if __has_builtin(__builtin_amdgcn_sdot4)
    return __builtin_amdgcn_sdot4(a, b, c, false);
#else
    c += (int)(signed char)(a & 0xff)        * (int)(signed char)(b & 0xff);
    c += (int)(signed char)((a >> 8) & 0xff) * (int)(signed char)((b >> 8) & 0xff);
    c += (int)(signed char)((a >> 16)& 0xff) * (int)(signed char)((b >> 16)& 0xff);
    c += (int)(signed char)(a >> 24)         * (int)(signed char)(b >> 24);
    return c;
#endif
}

// ---------- init: zero the two absmax slots ----------
__global__ void init_kernel(unsigned* mbits) {
    mbits[0] = 0u;
    mbits[1] = 0u;
}

// ---------- absmax reduction (float4 grid-stride, atomicMax on bits) ----------
__global__ __launch_bounds__(256) void absmax_kernel(const float* __restrict__ p,
                                                     int n4, unsigned* out) {
    float m = 0.f;
    int stride = gridDim.x * blockDim.x;
    for (int i = blockIdx.x * blockDim.x + threadIdx.x; i < n4; i += stride) {
        float4 v = ((const float4*)p)[i];
        m = fmaxf(m, fmaxf(fmaxf(fabsf(v.x), fabsf(v.y)),
                           fmaxf(fabsf(v.z), fabsf(v.w))));
    }
    #pragma unroll
    for (int off = 32; off; off >>= 1) m = fmaxf(m, __shfl_down(m, off));
    __shared__ float red[4];
    int lane = threadIdx.x & 63, wv = threadIdx.x >> 6;
    if (lane == 0) red[wv] = m;
    __syncthreads();
    if (threadIdx.x == 0) {
        m = fmaxf(fmaxf(red[0], red[1]), fmaxf(red[2], red[3]));
        atomicMax(out, __float_as_uint(m));
    }
}

// ---------- quantize x: NCHW fp32 -> NHWC int8 (LDS transpose per (b,h)) ----------
__global__ __launch_bounds__(256) void quant_x_kernel(const float* __restrict__ x,
                                                      signed char* __restrict__ qx,
                                                      const unsigned* __restrict__ mbits) {
    __shared__ signed char tile[WW * 132];          // ci-dim padded 128->132 (bank spread)
    const int bh = blockIdx.x;
    const int b = bh / HH, h = bh % HH;
    const float s = __uint_as_float(mbits[0]) / QDIV;
    const float* src = x + (size_t)b * CIN * HH * WW + (size_t)h * WW;  // + ci*HH*WW + w

    // read coalesced (w fastest), quantize, write transposed bytes into LDS
    for (int e = threadIdx.x; e < CIN * WW; e += 256) {
        int ci = e / WW, w = e % WW;
        float v = src[(size_t)ci * (HH * WW) + w];
        float q = rintf(v / s);
        q = fminf(fmaxf(q, -8.f), 7.f);
        tile[w * 132 + ci] = (signed char)q;
    }
    __syncthreads();

    // write out compact NHWC dwords, fully coalesced
    int* dst = (int*)(qx + (size_t)bh * (WW * CIN));
    for (int e = threadIdx.x; e < (WW * CIN) / 4; e += 256) {  // 1792 dwords, 7 iters
        int w = e >> 5, c4 = e & 31;
        int v = *(const int*)&tile[w * 132 + c4 * 4];
        dst[e] = v;
    }
}

// ---------- quantize weight: OIHW fp32 -> [k=kh*3+kw][ci/4][co] packed dwords ----------
__global__ __launch_bounds__(256) void quant_w_kernel(const float* __restrict__ wsrc,
                                                      int* __restrict__ qw,
                                                      const unsigned* __restrict__ mbits) {
    int idx = blockIdx.x * 256 + threadIdx.x;       // 9*32*256 = 73728
    int co = idx & 255;
    int c4 = (idx >> 8) & 31;
    int k  = idx >> 13;                              // 0..8
    int kh = k / 3, kw = k % 3;
    float s = __uint_as_float(mbits[1]) / QDIV;
    int pack = 0;
    #pragma unroll
    for (int j = 0; j < 4; ++j) {
        int ci = c4 * 4 + j;
        float v = wsrc[(((size_t)co * CIN + ci) * 3 + kh) * 3 + kw];
        float q = fminf(fmaxf(rintf(v / s), -8.f), 7.f);
        pack |= (((int)q) & 0xFF) << (8 * j);
    }
    qw[idx] = pack;
}

// ---------- conv: implicit GEMM via sdot4; lanes = co, 4 pixels/thread ----------
__global__ __launch_bounds__(256) void conv_kernel(const int* __restrict__ qx,
                                                   const int* __restrict__ qw,
                                                   const unsigned* __restrict__ mbits,
                                                   const float* __restrict__ bias,
                                                   float* __restrict__ out) {
    const int co = threadIdx.x;
    const int pix0 = blockIdx.x * 4;                // 4 consecutive w, never crosses a row
    const int b = pix0 / (HH * WW);
    const int rem = pix0 % (HH * WW);
    const int h = rem / WW;
    const int w0 = rem % WW;

    int acc0 = 0, acc1 = 0, acc2 = 0, acc3 = 0;

    #pragma unroll
    for (int kh = 0; kh < 3; ++kh) {
        const int hy = h + kh - 1;
        if (hy < 0 || hy >= HH) continue;
        const int* xrow = qx + ((b * HH + hy) * WW) * (CIN / 4);
        #pragma unroll
        for (int kw = 0; kw < 3; ++kw) {
            const int wx0 = w0 + kw - 1;            // pixel p reads wx0+p
            const int* wvp = qw + ((kh * 3 + kw) * (CIN / 4)) * COUT + co;
            const bool ok_lo = (wx0 >= 0);
            const bool ok_hi = (wx0 + 3 < WW);
            #pragma unroll
            for (int c4 = 0; c4 < CIN / 4; ++c4) {
                const int wv = wvp[c4 * COUT];
                int x0 = ok_lo ? xrow[wx0 * 32 + c4]       : 0;
                int x1 =         xrow[(wx0 + 1) * 32 + c4];
                int x2 =         xrow[(wx0 + 2) * 32 + c4];
                int x3 = ok_hi ? xrow[(wx0 + 3) * 32 + c4] : 0;
                acc0 = dot4(x0, wv, acc0);
                acc1 = dot4(x1, wv, acc1);
                acc2 = dot4(x2, wv, acc2);
                acc3 = dot4(x3, wv, acc3);
            }
        }
    }

    const float s = (__uint_as_float(mbits[0]) / QDIV) * (__uint_as_float(mbits[1]) / QDIV);
    const float bv = bias[co];
    float4 o;
    o.x = (float)acc0 * s + bv;
    o.y = (float)acc1 * s + bv;
    o.z = (float)acc2 * s + bv;
    o.w = (float)acc3 * s + bv;
    *(float4*)(out + (((size_t)(b * COUT + co) * HH + h) * WW + w0)) = o;
}

extern "C" void kernel_launch(void* const* d_in, const int* in_sizes, int n_in,
                              void* d_out, int out_size, void* d_ws, size_t ws_size,
                              hipStream_t stream) {
    const float* x    = (const float*)d_in[0];
    const float* w    = (const float*)d_in[1];
    const float* bias = (const float*)d_in[2];
    float* out = (float*)d_out;

    unsigned* mbits = (unsigned*)d_ws;
    signed char* qx = (signed char*)d_ws + 256;
    int* qw = (int*)((char*)d_ws + 256 + (size_t)B_ * HH * WW * CIN);

    hipLaunchKernelGGL(init_kernel, dim3(1), dim3(1), 0, stream, mbits);
    hipLaunchKernelGGL(absmax_kernel, dim3(2048), dim3(256), 0, stream,
                       x, B_ * CIN * HH * WW / 4, mbits + 0);
    hipLaunchKernelGGL(absmax_kernel, dim3(288), dim3(256), 0, stream,
                       w, COUT * CIN * 9 / 4, mbits + 1);
    hipLaunchKernelGGL(quant_x_kernel, dim3(B_ * HH), dim3(256), 0, stream,
                       x, qx, mbits);
    hipLaunchKernelGGL(quant_w_kernel, dim3(288), dim3(256), 0, stream,
                       w, qw, mbits);
    hipLaunchKernelGGL(conv_kernel, dim3(B_ * HH * WW / 4), dim3(256), 0, stream,
                       (const int*)qx, (const int*)qw, mbits, bias, out);
}

// Round 2
// 123.127 us; speedup vs baseline: 13.3599x; 13.3599x over previous
//
#include <hip/hip_runtime.h>
#include <stdint.h>

#define B_   32
#define CIN  128
#define HH   56
#define WW   56
#define COUT 256
#define QDIV 7.5f

typedef int v4i  __attribute__((ext_vector_type(4)));
typedef int v16i __attribute__((ext_vector_type(16)));

// ---------- init: zero the two absmax slots ----------
__global__ void init_kernel(unsigned* mbits) {
    mbits[0] = 0u;
    mbits[1] = 0u;
}

// ---------- absmax reduction (float4 grid-stride, atomicMax on bits) ----------
__global__ __launch_bounds__(256) void absmax_kernel(const float* __restrict__ p,
                                                     int n4, unsigned* out) {
    float m = 0.f;
    int stride = gridDim.x * blockDim.x;
    for (int i = blockIdx.x * blockDim.x + threadIdx.x; i < n4; i += stride) {
        float4 v = ((const float4*)p)[i];
        m = fmaxf(m, fmaxf(fmaxf(fabsf(v.x), fabsf(v.y)),
                           fmaxf(fabsf(v.z), fabsf(v.w))));
    }
    #pragma unroll
    for (int off = 32; off; off >>= 1) m = fmaxf(m, __shfl_down(m, off));
    __shared__ float red[4];
    int lane = threadIdx.x & 63, wv = threadIdx.x >> 6;
    if (lane == 0) red[wv] = m;
    __syncthreads();
    if (threadIdx.x == 0) {
        m = fmaxf(fmaxf(red[0], red[1]), fmaxf(red[2], red[3]));
        atomicMax(out, __float_as_uint(m));
    }
}

// ---------- quantize x: NCHW fp32 -> swizzled NHWC int8 ----------
// Global layout per (b,h) row: pixel w occupies bytes [w*128, w*128+128);
// byte o within the pixel holds ci = o ^ (((w+1)&7)<<4)  (slot-keyed XOR swizzle,
// slot = w+1 = where this pixel lands in the conv kernel's LDS row).
__global__ __launch_bounds__(256) void quant_x_kernel(const float* __restrict__ x,
                                                      signed char* __restrict__ qx,
                                                      const unsigned* __restrict__ mbits) {
    __shared__ signed char tile[WW * 132];          // ci padded 128->132
    const int bh = blockIdx.x;
    const int b = bh / HH, h = bh % HH;
    const float s = __uint_as_float(mbits[0]) / QDIV;
    const float* src = x + (size_t)b * (CIN * HH * WW) + (size_t)h * WW;

    for (int e = threadIdx.x; e < CIN * WW; e += 256) {
        int ci = e / WW, w = e - ci * WW;
        float v = src[(size_t)ci * (HH * WW) + w];
        float q = fminf(fmaxf(rintf(v / s), -8.f), 7.f);
        tile[w * 132 + ci] = (signed char)q;
    }
    __syncthreads();

    int* dst = (int*)(qx + (size_t)bh * (WW * CIN));
    for (int d = threadIdx.x; d < WW * 32; d += 256) {   // 1792 dwords
        int w = d >> 5, dw = d & 31;
        int src_dw = dw ^ (((w + 1) & 7) << 2);          // 16B-granular XOR
        dst[d] = *(const int*)&tile[w * 132 + src_dw * 4];
    }
}

// ---------- quantize weight: OIHW fp32 -> [tap][cc][co][32B ci-chunk] ----------
// byte addr = ((t*4+cc)*256 + co)*32 + (ci - cc*32); an A-fragment for the MFMA
// (lane l: co = base+(l&31), k-bytes (l>>5)*16..+15) is a single coalesced 16B load.
__global__ __launch_bounds__(256) void quant_w_kernel(const float* __restrict__ wsrc,
                                                      int* __restrict__ qw,
                                                      const unsigned* __restrict__ mbits) {
    int d = blockIdx.x * 256 + threadIdx.x;         // 73728 dwords total
    int t   = d >> 13;                               // tap 0..8
    int cc  = (d >> 11) & 3;                         // ci chunk of 32
    int co  = (d >> 3) & 255;
    int dw8 = d & 7;                                 // dword within 32B
    int kh = t / 3, kw = t % 3;
    float s = __uint_as_float(mbits[1]) / QDIV;
    int pack = 0;
    #pragma unroll
    for (int j = 0; j < 4; ++j) {
        int ci = cc * 32 + dw8 * 4 + j;
        float v = wsrc[(((size_t)co * CIN + ci) * 3 + kh) * 3 + kw];
        float q = fminf(fmaxf(rintf(v / s), -8.f), 7.f);
        pack |= (((int)q) & 0xFF) << (8 * j);
    }
    qw[d] = pack;
}

// ---------- conv: implicit GEMM on i8 MFMA ----------
// Block: 256 co x 2 image rows (128 px, 64-padded per row). 4 waves; wave wid
// owns co [wid*64, wid*64+64). acc[2][4]: 2 co-tiles x {row0 px0-31, px32-63,
// row1 px0-31, px32-63}. K = 9 taps x 4 ci-chunks of 32.
__global__ __launch_bounds__(256, 2) void conv_mfma_kernel(
        const signed char* __restrict__ qx,
        const signed char* __restrict__ qw2,
        const unsigned* __restrict__ mbits,
        const float* __restrict__ bias,
        float* __restrict__ out) {
    __shared__ signed char xs[4 * 8192];   // 4 input rows x 64 slots x 128B

    const int bid = blockIdx.x;
    const int b  = bid / (HH / 2);
    const int hp = bid % (HH / 2);
    const int h0 = hp * 2;

    const int tid   = threadIdx.x;
    const int wid   = tid >> 6;
    const int lane  = tid & 63;
    const int l31   = lane & 31;
    const int lhalf = lane >> 5;

    // ---- stage input rows h0-1 .. h0+2 (wave wid stages LDS row wid) ----
    {
        const int hy = h0 - 1 + wid;
        int4* rb = (int4*)(xs + wid * 8192);
        const int4 z = {0, 0, 0, 0};
        if (hy >= 0 && hy < HH) {
            const int4* src = (const int4*)(qx + (size_t)(b * HH + hy) * (WW * CIN));
            #pragma unroll
            for (int i = 0; i < 7; ++i) rb[8 + lane + i * 64] = src[lane + i * 64];
            rb[(lane < 8) ? lane : (448 + lane)] = z;   // zero slot 0 and slots 57-63
        } else {
            #pragma unroll
            for (int i = 0; i < 8; ++i) rb[lane + i * 64] = z;  // whole row zero
        }
    }
    __syncthreads();

    v16i acc[2][4];
    {
        v16i zz;
        #pragma unroll
        for (int r = 0; r < 16; ++r) zz[r] = 0;
        #pragma unroll
        for (int mi = 0; mi < 2; ++mi)
            #pragma unroll
            for (int ni = 0; ni < 4; ++ni) acc[mi][ni] = zz;
    }

    const int co_lane = wid * 64 + l31;
    #pragma unroll
    for (int kh = 0; kh < 3; ++kh) {
        #pragma unroll
        for (int kw = 0; kw < 3; ++kw) {
            const int t = kh * 3 + kw;
            #pragma unroll
            for (int cc = 0; cc < 4; ++cc) {
                const signed char* wp = qw2 + ((size_t)((t * 4 + cc) * 256 + co_lane)) * 32
                                        + lhalf * 16;
                v4i a0 = *(const v4i*)wp;            // co-tile mi=0
                v4i a1 = *(const v4i*)(wp + 1024);   // co-tile mi=1 (+32 co * 32B)
                #pragma unroll
                for (int ni = 0; ni < 4; ++ni) {
                    const int p = (ni & 1) * 32 + l31;          // pixel within row
                    const int slot = min(p + kw, 63);            // w' + 1, clamped
                    const int byteofs = (cc * 32 + lhalf * 16) ^ ((slot & 7) << 4);
                    const v4i bf = *(const v4i*)(xs + (kh + (ni >> 1)) * 8192
                                                 + slot * 128 + byteofs);
                    acc[0][ni] = __builtin_amdgcn_mfma_i32_32x32x32_i8(a0, bf, acc[0][ni], 0, 0, 0);
                    acc[1][ni] = __builtin_amdgcn_mfma_i32_32x32x32_i8(a1, bf, acc[1][ni], 0, 0, 0);
                }
            }
        }
    }

    // ---- epilogue: dequant + bias, store fp32 ----
    const float s = (__uint_as_float(mbits[0]) / QDIV) *
                    (__uint_as_float(mbits[1]) / QDIV);
    #pragma unroll
    for (int mi = 0; mi < 2; ++mi) {
        #pragma unroll
        for (int r = 0; r < 16; ++r) {
            const int co = wid * 64 + mi * 32 + (r & 3) + 8 * (r >> 2) + 4 * lhalf;
            const float bv = bias[co];
            float* orow = out + (((size_t)(b * COUT + co) * HH) + h0) * WW;
            #pragma unroll
            for (int ni = 0; ni < 4; ++ni) {
                const int p = (ni & 1) * 32 + l31;
                if (p < WW) orow[(ni >> 1) * WW + p] = (float)acc[mi][ni][r] * s + bv;
            }
        }
    }
}

extern "C" void kernel_launch(void* const* d_in, const int* in_sizes, int n_in,
                              void* d_out, int out_size, void* d_ws, size_t ws_size,
                              hipStream_t stream) {
    const float* x    = (const float*)d_in[0];
    const float* w    = (const float*)d_in[1];
    const float* bias = (const float*)d_in[2];
    float* out = (float*)d_out;

    unsigned* mbits = (unsigned*)d_ws;
    signed char* qx = (signed char*)d_ws + 256;
    signed char* qw2 = (signed char*)d_ws + 256 + (size_t)B_ * HH * WW * CIN;

    hipLaunchKernelGGL(init_kernel, dim3(1), dim3(1), 0, stream, mbits);
    hipLaunchKernelGGL(absmax_kernel, dim3(2048), dim3(256), 0, stream,
                       x, B_ * CIN * HH * WW / 4, mbits + 0);
    hipLaunchKernelGGL(absmax_kernel, dim3(288), dim3(256), 0, stream,
                       w, COUT * CIN * 9 / 4, mbits + 1);
    hipLaunchKernelGGL(quant_x_kernel, dim3(B_ * HH), dim3(256), 0, stream,
                       x, qx, mbits);
    hipLaunchKernelGGL(quant_w_kernel, dim3(288), dim3(256), 0, stream,
                       w, (int*)qw2, mbits);
    hipLaunchKernelGGL(conv_mfma_kernel, dim3(B_ * (HH / 2)), dim3(256), 0, stream,
                       qx, qw2, mbits, bias, out);
}

// Round 3
// 109.180 us; speedup vs baseline: 15.0665x; 1.1277x over previous
//
#include <hip/hip_runtime.h>
#include <stdint.h>

#define B_   32
#define CIN  128
#define HH   56
#define WW   56
#define COUT 256
#define QDIV 7.5f

#define NBLK_AX 2048
#define NBLK_AW 288
#define NBLK_QX (B_ * HH)   // 1792
#define NBLK_QW 288

typedef int v4i  __attribute__((ext_vector_type(4)));
typedef int v16i __attribute__((ext_vector_type(16)));

typedef __attribute__((address_space(3))) unsigned char lds_u8;
typedef __attribute__((address_space(1))) const unsigned char glb_u8;

__device__ __forceinline__ void load_lds16(const void* g, void* l) {
    __builtin_amdgcn_global_load_lds((glb_u8*)g, (lds_u8*)l, 16, 0, 0);
}

// ---------- absmax: blocks [0,2048) -> x, [2048,2336) -> w ----------
__global__ __launch_bounds__(256) void absmax_all_kernel(const float* __restrict__ x,
                                                         const float* __restrict__ w,
                                                         unsigned* __restrict__ mbits) {
    const float* p; int n4, i, stride; unsigned* slot;
    if (blockIdx.x < NBLK_AX) {
        p = x; n4 = B_ * CIN * HH * WW / 4;
        i = blockIdx.x * 256 + threadIdx.x; stride = NBLK_AX * 256; slot = mbits;
    } else {
        p = w; n4 = COUT * CIN * 9 / 4;
        i = (blockIdx.x - NBLK_AX) * 256 + threadIdx.x; stride = NBLK_AW * 256; slot = mbits + 1;
    }
    float m = 0.f;
    for (; i < n4; i += stride) {
        float4 v = ((const float4*)p)[i];
        m = fmaxf(m, fmaxf(fmaxf(fabsf(v.x), fabsf(v.y)),
                           fmaxf(fabsf(v.z), fabsf(v.w))));
    }
    #pragma unroll
    for (int off = 32; off; off >>= 1) m = fmaxf(m, __shfl_down(m, off));
    __shared__ float red[4];
    int lane = threadIdx.x & 63, wv = threadIdx.x >> 6;
    if (lane == 0) red[wv] = m;
    __syncthreads();
    if (threadIdx.x == 0) {
        m = fmaxf(fmaxf(red[0], red[1]), fmaxf(red[2], red[3]));
        atomicMax(slot, __float_as_uint(m));
    }
}

// ---------- quantize: blocks [0,1792) -> x, [1792,2080) -> w ----------
// qx: per (b,h) row, pixel w bytes [w*128,+128), byte o holds ci = o ^ (((w+1)&7)<<4)
// qw: dword d = ((((t*2+cch)*2+cc1)*2+kh16)*256+co)*4+dw4; ci = (cch*2+cc1)*32+kh16*16+dw4*4+j
__global__ __launch_bounds__(256) void quant_all_kernel(const float* __restrict__ x,
                                                        const float* __restrict__ w,
                                                        signed char* __restrict__ qx,
                                                        int* __restrict__ qw,
                                                        const unsigned* __restrict__ mbits) {
    if (blockIdx.x < NBLK_QX) {
        __shared__ signed char tile[WW * 132];
        const int bh = blockIdx.x;
        const int b = bh / HH, h = bh % HH;
        const float s = __uint_as_float(mbits[0]) / QDIV;
        const float* src = x + (size_t)b * (CIN * HH * WW) + (size_t)h * WW;
        for (int e = threadIdx.x; e < CIN * WW; e += 256) {
            int ci = e / WW, ww = e - ci * WW;
            float v = src[(size_t)ci * (HH * WW) + ww];
            float q = fminf(fmaxf(rintf(v / s), -8.f), 7.f);
            tile[ww * 132 + ci] = (signed char)q;
        }
        __syncthreads();
        int* dst = (int*)(qx + (size_t)bh * (WW * CIN));
        for (int d = threadIdx.x; d < WW * 32; d += 256) {
            int ww = d >> 5, dw = d & 31;
            int src_dw = dw ^ (((ww + 1) & 7) << 2);
            dst[d] = *(const int*)&tile[ww * 132 + src_dw * 4];
        }
    } else {
        int d = (blockIdx.x - NBLK_QX) * 256 + threadIdx.x;  // 73728 dwords
        int dw4  = d & 3;
        int co   = (d >> 2) & 255;
        int kh16 = (d >> 10) & 1;
        int cc   = (d >> 11) & 3;          // cch*2 + cc1
        int t    = d >> 13;
        int kh = t / 3, kw = t % 3;
        float s = __uint_as_float(mbits[1]) / QDIV;
        int pack = 0;
        #pragma unroll
        for (int j = 0; j < 4; ++j) {
            int ci = cc * 32 + kh16 * 16 + dw4 * 4 + j;
            float v = w[(((size_t)co * CIN + ci) * 3 + kh) * 3 + kw];
            float q = fminf(fmaxf(rintf(v / s), -8.f), 7.f);
            pack |= (((int)q) & 0xFF) << (8 * j);
        }
        qw[d] = pack;
    }
}

// ---------- conv: 2-phase pipelined i8-MFMA implicit GEMM ----------
// Block: 256 thr / 4 waves; 256 co x 2 rows (2x 64px-tiles of 32).
// Wave (wr=wid&1: co-half, wc=wid>>1: row) computes acc[4][2] (128 co x 64 px).
// LDS: xs [4 rows][58 slots][128B] = 29696 B; weight dbuf 2 x 16384 B. Total 62464.
// 18 weight segments (tap t, cc-half), double-buffered, staged via global_load_lds.
__global__ __launch_bounds__(256, 2) void conv_mfma_kernel(
        const signed char* __restrict__ qx,
        const signed char* __restrict__ qw2,
        const unsigned* __restrict__ mbits,
        const float* __restrict__ bias,
        float* __restrict__ out) {
    __shared__ signed char lds[29696 + 2 * 16384];

    // XCD-chunked swizzle (896 % 8 == 0 -> bijective)
    const int sbid = (blockIdx.x & 7) * 112 + (blockIdx.x >> 3);
    const int b  = sbid / 28;
    const int h0 = (sbid % 28) * 2;

    const int tid   = threadIdx.x;
    const int wid   = tid >> 6;
    const int lane  = tid & 63;
    const int l31   = lane & 31;
    const int lhalf = lane >> 5;
    const int wr    = wid & 1;    // co-half
    const int wc    = wid >> 1;   // row within block

    // ---- zero xs ----
    #pragma unroll
    for (int i = 0; i < 8; ++i) {
        int o = tid * 16 + i * 4096;
        if (o < 29696) *(int4*)(lds + o) = int4{0, 0, 0, 0};
    }
    __syncthreads();

    // ---- stage x rows (valid interiors) + weight segment 0 ----
    for (int j = wid; j < 28; j += 4) {              // 4 rows x 7 chunks
        const int r = j / 7, c = j - r * 7;
        const int hy = h0 - 1 + r;
        if (hy >= 0 && hy < HH) {
            const signed char* src = qx + (size_t)(b * HH + hy) * (WW * CIN) + (c * 64 + lane) * 16;
            load_lds16(src, lds + r * 7424 + 128 + (c * 64 + lane) * 16);
        }
    }
    {
        const signed char* gs = qw2 + tid * 16;
        signed char* ls = lds + 29696 + tid * 16;
        load_lds16(gs,         ls);
        load_lds16(gs + 4096,  ls + 4096);
        load_lds16(gs + 8192,  ls + 8192);
        load_lds16(gs + 12288, ls + 12288);
    }
    __syncthreads();   // drains vmcnt+lgkmcnt

    v16i acc[4][2];
    #pragma unroll
    for (int mi = 0; mi < 4; ++mi)
        #pragma unroll
        for (int ni = 0; ni < 2; ++ni)
            #pragma unroll
            for (int r = 0; r < 16; ++r) acc[mi][ni][r] = 0;

    #pragma unroll
    for (int s = 0; s < 18; ++s) {
        // stage next segment into the other buffer (overlaps this segment's MFMAs)
        if (s < 17) {
            const signed char* gs = qw2 + (s + 1) * 16384 + tid * 16;
            signed char* ls = lds + 29696 + ((s + 1) & 1) * 16384 + tid * 16;
            load_lds16(gs,         ls);
            load_lds16(gs + 4096,  ls + 4096);
            load_lds16(gs + 8192,  ls + 8192);
            load_lds16(gs + 12288, ls + 12288);
        }
        const int t  = s >> 1;
        const int kh = t / 3, kw = t % 3;
        const signed char* wb = lds + 29696 + (s & 1) * 16384;
        const signed char* xrow = lds + (wc + kh) * 7424;

        #pragma unroll
        for (int cc1 = 0; cc1 < 2; ++cc1) {
            const int cc = (s & 1) * 2 + cc1;
            v4i a[4];
            #pragma unroll
            for (int mi = 0; mi < 4; ++mi)
                a[mi] = *(const v4i*)(wb + cc1 * 8192 + lhalf * 4096 + wr * 2048 + mi * 512 + l31 * 16);
            #pragma unroll
            for (int ni = 0; ni < 2; ++ni) {
                int slot = ni * 32 + l31 + kw;
                if (slot > 57) slot = 57;                  // clamped lanes read zeros
                const v4i bf = *(const v4i*)(xrow + slot * 128 +
                                             ((cc * 32 + lhalf * 16) ^ ((slot & 7) << 4)));
                #pragma unroll
                for (int mi = 0; mi < 4; ++mi)
                    acc[mi][ni] = __builtin_amdgcn_mfma_i32_32x32x32_i8(a[mi], bf, acc[mi][ni], 0, 0, 0);
            }
        }
        __syncthreads();   // drains the staged loads (vmcnt) + publishes buffer flip
    }

    // ---- epilogue: dequant + bias ----
    const float s = (__uint_as_float(mbits[0]) / QDIV) *
                    (__uint_as_float(mbits[1]) / QDIV);
    const int hrow = h0 + wc;
    #pragma unroll
    for (int mi = 0; mi < 4; ++mi) {
        #pragma unroll
        for (int r = 0; r < 16; ++r) {
            const int co = wr * 128 + mi * 32 + (r & 3) + 8 * (r >> 2) + 4 * lhalf;
            const float bv = bias[co];
            float* orow = out + ((size_t)(b * COUT + co) * HH + hrow) * WW;
            orow[l31] = (float)acc[mi][0][r] * s + bv;
            if (l31 < WW - 32) orow[32 + l31] = (float)acc[mi][1][r] * s + bv;
        }
    }
}

extern "C" void kernel_launch(void* const* d_in, const int* in_sizes, int n_in,
                              void* d_out, int out_size, void* d_ws, size_t ws_size,
                              hipStream_t stream) {
    const float* x    = (const float*)d_in[0];
    const float* w    = (const float*)d_in[1];
    const float* bias = (const float*)d_in[2];
    float* out = (float*)d_out;

    unsigned* mbits = (unsigned*)d_ws;
    signed char* qx  = (signed char*)d_ws + 256;
    signed char* qw2 = (signed char*)d_ws + 256 + (size_t)B_ * HH * WW * CIN;

    hipMemsetAsync(d_ws, 0, 8, stream);
    hipLaunchKernelGGL(absmax_all_kernel, dim3(NBLK_AX + NBLK_AW), dim3(256), 0, stream,
                       x, w, mbits);
    hipLaunchKernelGGL(quant_all_kernel, dim3(NBLK_QX + NBLK_QW), dim3(256), 0, stream,
                       x, w, qx, (int*)qw2, mbits);
    hipLaunchKernelGGL(conv_mfma_kernel, dim3(B_ * (HH / 2)), dim3(256), 0, stream,
                       qx, qw2, mbits, bias, out);
}

// Round 4
// 104.642 us; speedup vs baseline: 15.7199x; 1.0434x over previous
//
#include <hip/hip_runtime.h>
#include <stdint.h>

#define B_   32
#define CIN  128
#define HH   56
#define WW   56
#define COUT 256
#define QDIV 7.5f

#define NBLK_AX 2048
#define NBLK_AW 288
#define NBLK_QX (B_ * HH)   // 1792
#define NBLK_QW 288

#define XROW 7424              // 58 slots * 128 B
#define XS_BYTES (6 * XROW)    // 44544

typedef int v4i  __attribute__((ext_vector_type(4)));
typedef int v16i __attribute__((ext_vector_type(16)));

typedef __attribute__((address_space(3))) unsigned char lds_u8;
typedef __attribute__((address_space(1))) const unsigned char glb_u8;

__device__ __forceinline__ void load_lds16(const void* g, void* l) {
    __builtin_amdgcn_global_load_lds((glb_u8*)g, (lds_u8*)l, 16, 0, 0);
}

// ---------- absmax: blocks [0,2048) -> x, [2048,2336) -> w ----------
__global__ __launch_bounds__(256) void absmax_all_kernel(const float* __restrict__ x,
                                                         const float* __restrict__ w,
                                                         unsigned* __restrict__ mbits) {
    const float* p; int n4, i, stride; unsigned* slot;
    if (blockIdx.x < NBLK_AX) {
        p = x; n4 = B_ * CIN * HH * WW / 4;
        i = blockIdx.x * 256 + threadIdx.x; stride = NBLK_AX * 256; slot = mbits;
    } else {
        p = w; n4 = COUT * CIN * 9 / 4;
        i = (blockIdx.x - NBLK_AX) * 256 + threadIdx.x; stride = NBLK_AW * 256; slot = mbits + 1;
    }
    float m = 0.f;
    for (; i < n4; i += stride) {
        float4 v = ((const float4*)p)[i];
        m = fmaxf(m, fmaxf(fmaxf(fabsf(v.x), fabsf(v.y)),
                           fmaxf(fabsf(v.z), fabsf(v.w))));
    }
    #pragma unroll
    for (int off = 32; off; off >>= 1) m = fmaxf(m, __shfl_down(m, off));
    __shared__ float red[4];
    int lane = threadIdx.x & 63, wv = threadIdx.x >> 6;
    if (lane == 0) red[wv] = m;
    __syncthreads();
    if (threadIdx.x == 0) {
        m = fmaxf(fmaxf(red[0], red[1]), fmaxf(red[2], red[3]));
        atomicMax(slot, __float_as_uint(m));
    }
}

// ---------- quantize: blocks [0,1792) -> x, [1792,2080) -> w ----------
// qx: per (b,h) row, pixel w occupies bytes [w*128,+128); byte o holds
//     ci = o ^ (((w+1)&7)<<4)   (slot-keyed XOR swizzle, slot = w+1 in LDS)
// qw: byte addr = ((t*4+cc)*256 + co)*32 + (ci - cc*32);  t = kh*3+kw
__global__ __launch_bounds__(256) void quant_all_kernel(const float* __restrict__ x,
                                                        const float* __restrict__ w,
                                                        signed char* __restrict__ qx,
                                                        int* __restrict__ qw,
                                                        const unsigned* __restrict__ mbits) {
    if (blockIdx.x < NBLK_QX) {
        __shared__ signed char tile[WW * 132];
        const int bh = blockIdx.x;
        const int b = bh / HH, h = bh % HH;
        const float s = __uint_as_float(mbits[0]) / QDIV;
        const float* src = x + (size_t)b * (CIN * HH * WW) + (size_t)h * WW;
        for (int e = threadIdx.x; e < CIN * WW; e += 256) {
            int ci = e / WW, ww = e - ci * WW;
            float v = src[(size_t)ci * (HH * WW) + ww];
            float q = fminf(fmaxf(rintf(v / s), -8.f), 7.f);
            tile[ww * 132 + ci] = (signed char)q;
        }
        __syncthreads();
        int* dst = (int*)(qx + (size_t)bh * (WW * CIN));
        for (int d = threadIdx.x; d < WW * 32; d += 256) {
            int ww = d >> 5, dw = d & 31;
            int src_dw = dw ^ (((ww + 1) & 7) << 2);
            dst[d] = *(const int*)&tile[ww * 132 + src_dw * 4];
        }
    } else {
        int d = (blockIdx.x - NBLK_QX) * 256 + threadIdx.x;  // 73728 dwords
        int dw8 = d & 7;                    // dword within 32B ci-chunk
        int co  = (d >> 3) & 255;
        int cc  = (d >> 11) & 3;
        int t   = d >> 13;                  // 0..8
        int kh = t / 3, kw = t % 3;
        float s = __uint_as_float(mbits[1]) / QDIV;
        int pack = 0;
        #pragma unroll
        for (int j = 0; j < 4; ++j) {
            int ci = cc * 32 + dw8 * 4 + j;
            float v = w[(((size_t)co * CIN + ci) * 3 + kh) * 3 + kw];
            float q = fminf(fmaxf(rintf(v / s), -8.f), 7.f);
            pack |= (((int)q) & 0xFF) << (8 * j);
        }
        qw[d] = pack;
    }
}

// ---------- conv: barrier-free i8-MFMA implicit GEMM, weights in registers ----------
// Block: 512 thr / 8 waves; 256 co x 4 rows. Wave (wr=wid&3: co quarter,
// wc=wid>>2: row-pair) computes 64 co x 128 px -> acc[2][4].
// x staged once in LDS (6 rows x 58 slots x 128B); weights stream L2->VGPR
// with depth-3 rotating prefetch. No barriers in the K-loop.
__global__ __launch_bounds__(512, 2) void conv_mfma_kernel(
        const signed char* __restrict__ qx,
        const signed char* __restrict__ qw2,
        const unsigned* __restrict__ mbits,
        const float* __restrict__ bias,
        float* __restrict__ out) {
    __shared__ signed char xs[XS_BYTES];

    // XCD-chunked swizzle (448 % 8 == 0 -> bijective)
    const int sbid = (blockIdx.x & 7) * 56 + (blockIdx.x >> 3);
    const int b  = sbid / 14;
    const int h0 = (sbid % 14) * 4;

    const int tid   = threadIdx.x;
    const int wid   = tid >> 6;
    const int lane  = tid & 63;
    const int l31   = lane & 31;
    const int lhalf = lane >> 5;
    const int wr    = wid & 3;    // co quarter
    const int wc    = wid >> 2;   // row-pair (0/1)

    // ---- zero xs ----
    #pragma unroll
    for (int i = 0; i < 6; ++i) {
        int o = tid * 16 + i * 8192;
        if (o < XS_BYTES) *(int4*)(xs + o) = int4{0, 0, 0, 0};
    }
    __syncthreads();

    // ---- stage x rows h0-1 .. h0+4 (valid interiors) ----
    for (int j = wid; j < 42; j += 8) {              // 6 rows x 7 chunks
        const int r = j / 7, c = j - r * 7;
        const int hy = h0 - 1 + r;
        if (hy >= 0 && hy < HH) {
            const signed char* src = qx + (size_t)(b * HH + hy) * (WW * CIN) + (c * 64 + lane) * 16;
            load_lds16(src, xs + r * XROW + 128 + (c * 64 + lane) * 16);
        }
    }
    __syncthreads();

    v16i acc[2][4];
    #pragma unroll
    for (int mi = 0; mi < 2; ++mi)
        #pragma unroll
        for (int ni = 0; ni < 4; ++ni)
            #pragma unroll
            for (int r = 0; r < 16; ++r) acc[mi][ni][r] = 0;

    // weight fragment base: chunk k (= t*4+cc) at wbase + k*8192
    const int co_lane = wr * 64 + l31;
    const signed char* wbase = qw2 + (size_t)co_lane * 32 + lhalf * 16;

    v4i abuf[4][2];
    #pragma unroll
    for (int k0 = 0; k0 < 3; ++k0) {
        abuf[k0][0] = *(const v4i*)(wbase + k0 * 8192);
        abuf[k0][1] = *(const v4i*)(wbase + k0 * 8192 + 1024);
    }

    #pragma unroll
    for (int k = 0; k < 36; ++k) {
        if (k + 3 < 36) {      // depth-3 prefetch into rotating buffer (static idx)
            abuf[(k + 3) & 3][0] = *(const v4i*)(wbase + (k + 3) * 8192);
            abuf[(k + 3) & 3][1] = *(const v4i*)(wbase + (k + 3) * 8192 + 1024);
        }
        const int t  = k >> 2, cc = k & 3;
        const int kh = t / 3, kw = t - kh * 3;
        const signed char* x0 = xs + (wc * 2 + kh) * XROW;
        const int ko = cc * 32 + lhalf * 16;
        const v4i a0 = abuf[k & 3][0];
        const v4i a1 = abuf[k & 3][1];
        __builtin_amdgcn_s_setprio(1);
        #pragma unroll
        for (int ni = 0; ni < 4; ++ni) {
            int slot = (ni & 1) * 32 + l31 + kw;
            slot = slot > 57 ? 57 : slot;            // clamped lanes read zeros
            const v4i bf = *(const v4i*)(x0 + (ni >> 1) * XROW + slot * 128 +
                                         (ko ^ ((slot & 7) << 4)));
            acc[0][ni] = __builtin_amdgcn_mfma_i32_32x32x32_i8(a0, bf, acc[0][ni], 0, 0, 0);
            acc[1][ni] = __builtin_amdgcn_mfma_i32_32x32x32_i8(a1, bf, acc[1][ni], 0, 0, 0);
        }
        __builtin_amdgcn_s_setprio(0);
    }

    // ---- epilogue: dequant + bias ----
    const float s = (__uint_as_float(mbits[0]) / QDIV) *
                    (__uint_as_float(mbits[1]) / QDIV);
    #pragma unroll
    for (int mi = 0; mi < 2; ++mi) {
        #pragma unroll
        for (int r = 0; r < 16; ++r) {
            const int co = wr * 64 + mi * 32 + (r & 3) + 8 * (r >> 2) + 4 * lhalf;
            const float bv = bias[co];
            #pragma unroll
            for (int ni = 0; ni < 4; ++ni) {
                const int p = (ni & 1) * 32 + l31;
                const int hrow = h0 + wc * 2 + (ni >> 1);
                if (p < WW)
                    out[((size_t)(b * COUT + co) * HH + hrow) * WW + p] =
                        (float)acc[mi][ni][r] * s + bv;
            }
        }
    }
}

extern "C" void kernel_launch(void* const* d_in, const int* in_sizes, int n_in,
                              void* d_out, int out_size, void* d_ws, size_t ws_size,
                              hipStream_t stream) {
    const float* x    = (const float*)d_in[0];
    const float* w    = (const float*)d_in[1];
    const float* bias = (const float*)d_in[2];
    float* out = (float*)d_out;

    unsigned* mbits = (unsigned*)d_ws;
    signed char* qx  = (signed char*)d_ws + 256;
    signed char* qw2 = (signed char*)d_ws + 256 + (size_t)B_ * HH * WW * CIN;

    hipMemsetAsync(d_ws, 0, 8, stream);
    hipLaunchKernelGGL(absmax_all_kernel, dim3(NBLK_AX + NBLK_AW), dim3(256), 0, stream,
                       x, w, mbits);
    hipLaunchKernelGGL(quant_all_kernel, dim3(NBLK_QX + NBLK_QW), dim3(256), 0, stream,
                       x, w, qx, (int*)qw2, mbits);
    hipLaunchKernelGGL(conv_mfma_kernel, dim3(B_ * (HH / 4)), dim3(512), 0, stream,
                       qx, qw2, mbits, bias, out);
}